// Round 2
// baseline (1777.220 us; speedup 1.0000x reference)
//
#include <hip/hip_runtime.h>
#include <hip/hip_bf16.h>
#include <stdint.h>

// Problem constants
#define T_STEPS 256
#define B_SZ    4096
#define I_SZ    144
#define H_SZ    32
#define W_LD    176   // H + I

// photonic sigmoid constants
#define PS_A1   0.06f
#define PS_A2   1.005f
#define PS_X0   0.145f
#define PS_CUT  2.0f

typedef const __attribute__((address_space(1))) void* gptr_t;
typedef __attribute__((address_space(3))) void* lptr_t;

// -----------------------------------------------------------------------------
// Kernel 1: U[row][j] = sum_i x[row][i] * Wx[j][i] + b[j]
// Block = 64 threads = 1 wave, owns 64 rows. x tile staged global->LDS via
// global_load_lds (coalesced 1KB/instr), then thread-per-row compute with
// wave-uniform W addresses (s_load). No barrier needed: wave-private tile.
// -----------------------------------------------------------------------------
__global__ __launch_bounds__(64) void gemm_u(
    const float* __restrict__ x,     // [nrows][144] (chunk base)
    const float* __restrict__ W,     // [32][176], Wx = cols 32..175
    const float* __restrict__ bias,  // [32]
    float* __restrict__ U)           // [nrows][32]
{
    __shared__ __align__(16) float tile[64 * I_SZ];  // 36864 B -> 4 blocks/CU
    const int lane = threadIdx.x;
    const float* gsrc = x + (size_t)blockIdx.x * 64 * I_SZ;

    // 36 x (64 lanes x 16B) = 36 KB staged, all loads in flight (vmcnt<=36)
#pragma unroll
    for (int k = 0; k < 36; ++k) {
        __builtin_amdgcn_global_load_lds(
            (gptr_t)(gsrc + k * 256 + lane * 4),
            (lptr_t)(tile + k * 256),
            16, 0, 0);
    }

    float acc[H_SZ];
#pragma unroll
    for (int j = 0; j < H_SZ; ++j) acc[j] = bias[j];

    asm volatile("s_waitcnt vmcnt(0)" ::: "memory");

    const float* xr = tile + lane * I_SZ;   // 576B stride, 16B aligned
#pragma unroll 4
    for (int q = 0; q < I_SZ / 4; ++q) {
        float4 xv = *(const float4*)(xr + 4 * q);
#pragma unroll
        for (int j = 0; j < H_SZ; ++j) {
            // wave-uniform address -> scalar load into SGPRs
            float4 wv = *(const float4*)(W + j * W_LD + H_SZ + 4 * q);
            acc[j] = fmaf(xv.x, wv.x,
                     fmaf(xv.y, wv.y,
                     fmaf(xv.z, wv.z,
                     fmaf(xv.w, wv.w, acc[j]))));
        }
    }

    float* ur = U + ((size_t)blockIdx.x * 64 + lane) * H_SZ;
#pragma unroll
    for (int j = 0; j < H_SZ; j += 4) {
        *(float4*)(ur + j) = make_float4(acc[j], acc[j+1], acc[j+2], acc[j+3]);
    }
}

// -----------------------------------------------------------------------------
// Kernel 2: recurrence  h = ps(h @ Wh.T + U[t])
// Block = 256 threads = 4 waves = 8 batches. lane j = tid&31 holds h_j.
// h broadcast via __shfl width-32 (no LDS, no barriers). 4 split FMA chains.
// U prefetched 8 steps deep in registers (superstep ~1200cyc > 900cyc HBM).
// -----------------------------------------------------------------------------
__global__ __launch_bounds__(256) void recur(
    const float* __restrict__ U,     // [Tc][B][32]
    const float* __restrict__ W,     // [32][176], Wh = cols 0..31
    float* __restrict__ hout,        // [B][32] running h state / final output
    int Tc, int first)
{
    const int tid = threadIdx.x;
    const int j   = tid & 31;
    const int b   = blockIdx.x * 8 + (tid >> 5);

    // Wh row j -> 32 registers
    float wh[H_SZ];
#pragma unroll
    for (int k = 0; k < H_SZ; k += 4) {
        float4 wv = *(const float4*)(W + j * W_LD + k);
        wh[k] = wv.x; wh[k+1] = wv.y; wh[k+2] = wv.z; wh[k+3] = wv.w;
    }

    float h;
    if (first) h = 0.0f;
    else       h = hout[(size_t)b * H_SZ + j];

    const float*  Up     = U + (size_t)b * H_SZ + j;
    const size_t  stride = (size_t)B_SZ * H_SZ;

    const float expC = (float)(1.0 / (0.033 * 0.6931471805599453)); // 1/(D*ln2)

    // depth-8 register prefetch pipeline
    float un[8];
#pragma unroll
    for (int i = 0; i < 8; ++i) {
        int tn = (i < Tc) ? i : (Tc - 1);
        un[i] = Up[(size_t)tn * stride];
    }

    for (int t0 = 0; t0 < Tc; t0 += 8) {
        float cur[8];
#pragma unroll
        for (int i = 0; i < 8; ++i) cur[i] = un[i];
        // issue next superstep's loads now; consumed 8 steps later
#pragma unroll
        for (int i = 0; i < 8; ++i) {
            int tn = t0 + 8 + i;
            if (tn >= Tc) tn = Tc - 1;
            un[i] = Up[(size_t)tn * stride];
        }
#pragma unroll
        for (int i = 0; i < 8; ++i) {
            if (t0 + i < Tc) {
                float hb = h;
                float s0 = cur[i], s1 = 0.0f, s2 = 0.0f, s3 = 0.0f;
#pragma unroll
                for (int k = 0; k < H_SZ; k += 4) {
                    s0 = fmaf(wh[k+0], __shfl(hb, k+0, 32), s0);
                    s1 = fmaf(wh[k+1], __shfl(hb, k+1, 32), s1);
                    s2 = fmaf(wh[k+2], __shfl(hb, k+2, 32), s2);
                    s3 = fmaf(wh[k+3], __shfl(hb, k+3, 32), s3);
                }
                float z  = (s0 + s1) + (s2 + s3);
                float zz = fminf(z - PS_X0, PS_CUT);
                float e  = exp2f(zz * expC);
                h = PS_A2 + (PS_A1 - PS_A2) / (1.0f + e);
            }
        }
    }

    hout[(size_t)b * H_SZ + j] = h;
}

// -----------------------------------------------------------------------------
extern "C" void kernel_launch(void* const* d_in, const int* in_sizes, int n_in,
                              void* d_out, int out_size, void* d_ws, size_t ws_size,
                              hipStream_t stream)
{
    const float* x    = (const float*)d_in[0];  // [256][4096][144]
    const float* W    = (const float*)d_in[1];  // [32][176]
    const float* bias = (const float*)d_in[2];  // [32]
    float* out = (float*)d_out;                 // [4096][32]
    float* U   = (float*)d_ws;

    // choose T-chunk that fits in workspace
    int Tc = T_STEPS;
    while ((size_t)Tc * B_SZ * H_SZ * sizeof(float) > ws_size && Tc > 1) Tc >>= 1;

    for (int t0 = 0; t0 < T_STEPS; t0 += Tc) {
        int tc = (t0 + Tc <= T_STEPS) ? Tc : (T_STEPS - t0);
        int nrows = tc * B_SZ;
        gemm_u<<<nrows / 64, 64, 0, stream>>>(
            x + (size_t)t0 * B_SZ * I_SZ, W, bias, U);
        recur<<<B_SZ / 8, 256, 0, stream>>>(U, W, out, tc, t0 == 0 ? 1 : 0);
    }
}